// Round 6
// baseline (2818.568 us; speedup 1.0000x reference)
//
#include <hip/hip_runtime.h>

typedef _Float16 f16;
typedef _Float16 f16x4 __attribute__((ext_vector_type(4)));
typedef _Float16 f16x8 __attribute__((ext_vector_type(8)));
typedef float    f32x2 __attribute__((ext_vector_type(2)));
typedef float    f32x4 __attribute__((ext_vector_type(4)));

// K=16 f16 MFMA: A,B = f16x4 (one 8B load each), D = f32x4. Lane (lo + 16*q)
// holds k = q*4 + [0..3] for A(row=lo) and B(col=lo); C/D: col=lane&15,
// row=q*4+reg (shape-determined, same as the K=32 16x16 used through R14).
// Lets the 8B blocked-granule loads feed MFMA with ZERO repacking.
#if __has_builtin(__builtin_amdgcn_mfma_f32_16x16x16f16)
#define MFMA16x16(a,b,c) __builtin_amdgcn_mfma_f32_16x16x16f16((a),(b),(c),0,0,0)
#else
__device__ __forceinline__ f32x4 mfma16x16_asm(f16x4 a, f16x4 b, f32x4 c)
{
    asm("v_mfma_f32_16x16x16_f16 %0, %1, %2, %0" : "+v"(c) : "v"(a), "v"(b));
    return c;
}
#define MFMA16x16(a,b,c) mfma16x16_asm((a),(b),(c))
#endif

// R15/R16: agent-scope (sc1 = read the LLC coherence point, same scope the
// previous __hip_atomic_load AGENT used) 8B load as VOLATILE inline asm.
// Volatile asms keep mutual program order -> the full load batch is
// guaranteed outstanding together, which three rounds of source-level
// persuasion (R11 guards, R13 straight-line, R14 sched_barrier) could not
// get the backend to do (VGPR stuck at 120 = depth-3 interleave).
// Races: every slot read is strictly older than the last grid barrier.
// The compiler does NOT track these loads -> s_waitcnt vmcnt(0) ourselves
// before use + sched_barrier(0) so nothing hoists above the wait (rule #18).
// R16 hardening vs R15: no per-load "memory" clobber, no bw[] prefetch
// array (weights read inline from LDS during MFMA) -> peak RA pressure
// ~170/256, so RA never copies/spills an in-flight asm output.
#define GLOAD8(dst, p, imm) \
    asm volatile("global_load_dwordx2 %0, %1, off offset:" #imm " sc1" \
                 : "=v"(dst) : "v"(p))

constexpr unsigned NB = 64, NS = 256, NC = 64, NH = 512, NT = 128;
constexpr unsigned HSLOT = NB * NH;                       // f16 elems per h snapshot

// ---- workspace layout (total ~2.70 MB) ----
constexpr unsigned OFF_WX   = 0;                          // x BLOCKED f16 [256 t][16 c4][64 b][4] (2 MB)
constexpr unsigned OFF_WLIN = OFF_WX   + NB*NS*NC*2;      // lin_W as f16 [64][512]  (64 KB)
constexpr unsigned OFF_EH0  = OFF_WLIN + NC*NH*2;         // 4 h-rings, 2 slots each (512 KB)
constexpr unsigned OFF_EH1  = OFF_EH0  + 2*HSLOT*2;
constexpr unsigned OFF_DH0  = OFF_EH1  + 2*HSLOT*2;
constexpr unsigned OFF_DH1  = OFF_DH0  + 2*HSLOT*2;
constexpr unsigned OFF_BAR  = OFF_DH1  + 2*HSLOT*2;       // barrier ints (8 KB zeroed)

// h rings: BLOCKED layout, elem(batch b, unit u) at (u/4)*256 + b*4 + (u%4).
// Producer WG writes 64 batches x 8B = 512B contiguous, full lines, no
// cross-WG line sharing (R7: killed the partial-line RMW storm).

// ============================ prep kernel ============================
__global__ void prep_convert(const float* __restrict__ x,
                             const float* __restrict__ linw,
                             char* __restrict__ ws)
{
    unsigned rel = blockIdx.x * 256u + threadIdx.x;
    if (rel < 65536u) {
        // x [64 b][256 t][64 c] f32 -> blocked f16: elem(t,c,b) at
        // t*4096 + (c>>2)*256 + b*4 + (c&3). Thread: one (t,c4), 4 batches.
        unsigned t = rel >> 8, c4 = (rel >> 4) & 15u, b0 = (rel & 15u) << 2;
        #pragma unroll
        for (unsigned j = 0; j < 4; ++j) {
            float4 v = ((const float4*)x)[(b0 + j) * 4096u + t * 16u + c4];
            f16x4 o; o[0]=(f16)v.x; o[1]=(f16)v.y; o[2]=(f16)v.z; o[3]=(f16)v.w;
            ((f16x4*)(ws + OFF_WX))[t * 1024u + c4 * 64u + b0 + j] = o;
        }
    } else if ((rel -= 65536u) < 8192u) {
        float4 v = ((const float4*)linw)[rel];
        f16x4 o; o[0]=(f16)v.x; o[1]=(f16)v.y; o[2]=(f16)v.z; o[3]=(f16)v.w;
        ((f16x4*)(ws + OFF_WLIN))[rel] = o;
    } else if ((rel -= 8192u) < 32768u) {         // zero all 4 h rings (contiguous)
        f16x8 z = {};
        ((f16x8*)(ws + OFF_EH0))[rel] = z;
    } else if ((rel -= 32768u) < 512u) {          // zero barrier block (8 KB)
        int4 z; z.x = z.y = z.z = z.w = 0;
        ((int4*)(ws + OFF_BAR))[rel] = z;
    }
}

// ============================ device helpers ============================

__device__ __forceinline__ float sigm(float v)   { return 1.f / (1.f + __expf(-v)); }
__device__ __forceinline__ float tanh_f(float v) { return 2.f / (1.f + __expf(-2.f * v)) - 1.f; }

// Fine-grained device-coherent h STORE (write-through at coherence point).
__device__ __forceinline__ void h_store8(f16* p, f16x4 v)
{
    union { unsigned long long u; f16x4 h; } c; c.h = v;
    __hip_atomic_store((unsigned long long*)p, c.u, __ATOMIC_RELAXED, __HIP_MEMORY_SCOPE_AGENT);
}

// Barrier: R7-proven topology (16 groups x 16 WGs, root counter, 16
// distributed release-flag lines; 16 pollers per flag line). ALL RELAXED.
// Ordering is structural: leading __syncthreads drains all h stores
// (write-through, ack'd at coherence point) before tid0's arrival issues;
// consumer h loads bypass L2 and read the coherence point directly.
__device__ __forceinline__ void grid_barrier(int* bar, int wg, int tid, int& bgen)
{
    __syncthreads();                           // drain all threads' stores/loads
    if (tid == 0) {
        const int g = wg >> 4;                 // 16 groups of 16 WGs
        int* grp   = bar + g * 32;             // 128B-spaced counters
        int* root  = bar + 16 * 32;
        int* flags = bar + 17 * 32;            // 16 flag words, 128B apart
        const int target = bgen + 1;

        int old = __hip_atomic_fetch_add(grp, 1, __ATOMIC_RELAXED, __HIP_MEMORY_SCOPE_AGENT);
        if ((old & 15) == 15) {                // group complete
            int ro = __hip_atomic_fetch_add(root, 1, __ATOMIC_RELAXED, __HIP_MEMORY_SCOPE_AGENT);
            if ((ro & 15) == 15) {             // all 16 groups complete
                #pragma unroll
                for (int i = 0; i < 16; ++i)
                    __hip_atomic_store(flags + i * 32, target, __ATOMIC_RELAXED, __HIP_MEMORY_SCOPE_AGENT);
            }
        }
        int* myf = flags + g * 32;
        while (__hip_atomic_load(myf, __ATOMIC_RELAXED, __HIP_MEMORY_SCOPE_AGENT) < target)
            __builtin_amdgcn_s_sleep(1);
        bgen = target;
    }
    __syncthreads();
}

// load this WG's 16 weight rows ([A | B] concat along K) fp32 -> f16 LDS
__device__ __forceinline__ void load_wlds_f32(f16 (*Wlds)[1032],
                                              const float* __restrict__ A, int KA,
                                              const float* __restrict__ Bs, int KB,
                                              int u0, int tid)
{
    int nch = (KA + KB) >> 2;       // float4 chunks per row
    int tot = nch << 4;
    for (int idx = tid; idx < tot; idx += 256) {
        int j = idx / nch, ch = idx - j * nch;
        int k = ch << 2;
        int grow = ((j >> 2) << 9) + u0 + (j & 3);   // gate*512 + unit
        float4 v;
        if (k < KA) v = *(const float4*)(A + grow * KA + k);
        else        v = *(const float4*)(Bs + grow * KB + (k - KA));
        f16x4 o; o[0]=(f16)v.x; o[1]=(f16)v.y; o[2]=(f16)v.z; o[3]=(f16)v.w;
        *(f16x4*)&Wlds[j][k] = o;
    }
}

// decoder-L0 weights: rows = [Wfold = dec_Wih0 @ lin_W (512) | dec_Whh0 (512)]
__device__ __forceinline__ void load_wlds_fold(f16 (*Wlds)[1032],
                                               const float* __restrict__ dwih0,
                                               const float* __restrict__ linw,
                                               const float* __restrict__ dwhh0,
                                               int u0, int tid)
{
    {   // fold part: each thread computes 32 consecutive k in one row
        int idx = tid << 5;
        int j = idx >> 9, k0 = idx & 511;
        int grow = ((j >> 2) << 9) + u0 + (j & 3);
        float acc[32];
        #pragma unroll
        for (int q = 0; q < 32; ++q) acc[q] = 0.f;
        for (int c = 0; c < 64; ++c) {
            float wc = dwih0[grow * 64 + c];
            const float* lr = linw + c * 512 + k0;
            #pragma unroll
            for (int q = 0; q < 32; ++q) acc[q] += wc * lr[q];
        }
        #pragma unroll
        for (int q = 0; q < 32; ++q) Wlds[j][k0 + q] = (f16)acc[q];
    }
    int tot = 2048;                 // dwhh0 part: 16 rows x 128 float4
    for (int idx = tid; idx < tot; idx += 256) {
        int j = idx >> 7, ch = idx & 127, k = ch << 2;
        int grow = ((j >> 2) << 9) + u0 + (j & 3);
        float4 v = *(const float4*)(dwhh0 + grow * 512 + k);
        f16x4 o; o[0]=(f16)v.x; o[1]=(f16)v.y; o[2]=(f16)v.z; o[3]=(f16)v.w;
        *(f16x4*)&Wlds[j][512 + k] = o;
    }
}

// one recurrent step for this WG's 4 hidden units.
// Split-K: wave w covers slices [s0, s0+ns). EXACT => ns==MAXS for every
// wave. !EXACT => short waves load a clamped duplicate of their last slice,
// zeroed AFTER the vmcnt drain (MFMA with A=0 is a no-op).
// Per 32-slice: 2 K=16 windows; lane q takes k = win*16 + q*4 + [0..3];
// each A-fragment is ONE volatile asm 8B sc1 load; single s_waitcnt vmcnt(0)
// + sched_barrier(0); weight B-frags read inline from LDS in the MFMA loop.
template<int MAXS, bool EXACT>
__device__ __forceinline__ void rnn_round(f16 (*Wlds)[1032], float (*Dp)[64][17],
                                          const f16* __restrict__ A0, int K0,
                                          const f16* __restrict__ A1,
                                          int K, int kStart,
                                          const float* ba, float& creg,
                                          f16* __restrict__ ho,
                                          int u0, int tid)
{
    const int lane = tid & 63, wv = tid >> 6, q = lane >> 4, lo = lane & 15;
    const int sBeg = kStart >> 5, n = (K >> 5) - sBeg;
    const int per = n >> 2, rem = n & 3;
    const int s0 = sBeg + wv * per + (wv < rem ? wv : rem);
    const int ns = EXACT ? MAXS : (per + (wv < rem ? 1 : 0));

    int sEff[MAXS];                    // fully unrolled -> static indexing
    #pragma unroll
    for (int s = 0; s < MAXS; ++s)
        sEff[s] = s0 + (EXACT ? s : (s < ns ? s : ns - 1));

    // ---- load batch: MAXS*2 windows x 4 m-frags, all issued back-to-back ----
    f32x2 Ar[MAXS][2][4];
    #pragma unroll
    for (int s = 0; s < MAXS; ++s) {
        int kb = sEff[s] << 5;
        bool in0 = kb < K0;            // slice-uniform (K0 multiple of 32)
        const f16* src = in0 ? A0 : A1;           // SELECT, no branch
        int kbb = in0 ? kb : kb - K0;
        #pragma unroll
        for (int w = 0; w < 2; ++w) {
            int kr = kbb + (w << 4) + (q << 2);
            const f16* p = src + ((kr >> 2) << 8) + (lo << 2);
            GLOAD8(Ar[s][w][0], p, 0);      // m = lo       (+0   B)
            GLOAD8(Ar[s][w][1], p, 128);    // m = lo+16    (+128 B)
            GLOAD8(Ar[s][w][2], p, 256);    // m = lo+32
            GLOAD8(Ar[s][w][3], p, 384);    // m = lo+48
        }
    }

    asm volatile("s_waitcnt vmcnt(0)" ::: "memory");
    __builtin_amdgcn_sched_barrier(0);     // rule #18: nothing hoists above the wait

    if (!EXACT && MAXS - 1 >= ns) {        // zero the clamped duplicate slice
        f32x2 z = {0.f, 0.f};
        #pragma unroll
        for (int w = 0; w < 2; ++w)
            #pragma unroll
            for (int j = 0; j < 4; ++j)
                Ar[MAXS-1][w][j] = z;
    }

    f32x4 ac0 = {0.f,0.f,0.f,0.f}, ac1 = ac0, ac2 = ac0, ac3 = ac0;
    #pragma unroll
    for (int s = 0; s < MAXS; ++s)
        #pragma unroll
        for (int w = 0; w < 2; ++w) {
            f16x4 bf = *(const f16x4*)&Wlds[lo][(sEff[s] << 5) + (w << 4) + (q << 2)];
            ac0 = MFMA16x16(__builtin_bit_cast(f16x4, Ar[s][w][0]), bf, ac0);
            ac1 = MFMA16x16(__builtin_bit_cast(f16x4, Ar[s][w][1]), bf, ac1);
            ac2 = MFMA16x16(__builtin_bit_cast(f16x4, Ar[s][w][2]), bf, ac2);
            ac3 = MFMA16x16(__builtin_bit_cast(f16x4, Ar[s][w][3]), bf, ac3);
        }

    #pragma unroll
    for (int r = 0; r < 4; ++r) {
        int rr = (q << 2) + r;
        Dp[wv][rr     ][lo] = ac0[r];
        Dp[wv][rr + 16][lo] = ac1[r];
        Dp[wv][rr + 32][lo] = ac2[r];
        Dp[wv][rr + 48][lo] = ac3[r];
    }
    __syncthreads();
    const int m = tid >> 2, uu = tid & 3;
    float v[4];
    #pragma unroll
    for (int g = 0; g < 4; ++g) {
        int col = (g << 2) + uu;
        v[g] = Dp[0][m][col] + Dp[1][m][col] + Dp[2][m][col] + Dp[3][m][col] + ba[g];
    }
    float ii = sigm(v[0]), ff = sigm(v[1]), gg = tanh_f(v[2]), oo = sigm(v[3]);
    creg = ff * creg + ii * gg;
    float h = oo * tanh_f(creg);
    // pack the 4 gate-threads' h into one aligned 8B word; blocked layout:
    // this WG's block (u0/4) at +m*4 -> 64 batches x 8B = 512B contiguous.
    float h1 = __shfl_down(h, 1);
    float h2 = __shfl_down(h, 2);
    float h3 = __shfl_down(h, 3);
    if (uu == 0) {
        f16x4 hv; hv[0] = (f16)h; hv[1] = (f16)h1; hv[2] = (f16)h2; hv[3] = (f16)h3;
        h_store8(ho + ((u0 >> 2) << 8) + (m << 2), hv);
    }
}

// out_t tile: 16 batches x 64 cols = h1_t @ lin_W^T + lin_b  (H1 blocked)
// Same pattern: batched asm 8B loads, one vmcnt, K=16 MFMAs, weights read
// inline (plain cached loads from WLIN; compiler tracks its own waits).
__device__ __forceinline__ void out_gemm(const f16* __restrict__ H1,
                                         const f16* __restrict__ LW,
                                         const float* __restrict__ linb,
                                         float* __restrict__ out,
                                         int w, int t, int tid)
{
    const int lane = tid & 63, wv = tid >> 6, q = lane >> 4, lo = lane & 15;
    int b0 = w << 4;
    int c0 = wv << 4;

    f32x2 a[16][2];
    #pragma unroll
    for (int s = 0; s < 16; ++s)
        #pragma unroll
        for (int w2 = 0; w2 < 2; ++w2) {
            int kr = (s << 5) + (w2 << 4) + (q << 2);
            const f16* p = H1 + ((kr >> 2) << 8) + ((b0 + lo) << 2);
            GLOAD8(a[s][w2], p, 0);
        }

    asm volatile("s_waitcnt vmcnt(0)" ::: "memory");
    __builtin_amdgcn_sched_barrier(0);

    f32x4 ac = {0.f,0.f,0.f,0.f};
    #pragma unroll
    for (int s = 0; s < 16; ++s)
        #pragma unroll
        for (int w2 = 0; w2 < 2; ++w2) {
            f16x4 bf = *(const f16x4*)(LW + (c0 + lo) * 512 + (s << 5) + (w2 << 4) + (q << 2));
            ac = MFMA16x16(__builtin_bit_cast(f16x4, a[s][w2]), bf, ac);
        }

    float lb = linb[c0 + lo];
    #pragma unroll
    for (int r = 0; r < 4; ++r) {
        int b = b0 + (q << 2) + r;
        out[(size_t)b * (NT * NC) + t * NC + c0 + lo] = ac[r] + lb;
    }
}

// ============================ main persistent kernel ============================
// Plain (non-cooperative) launch: 256 WGs x 256 thr, 50.4 KB LDS/WG.
// __launch_bounds__(256,2): VGPR cap 256 (the live load batch costs 128)
// while keeping capacity >= 2 WGs/CU (512 slots >= 256 WGs), so the whole
// grid stays co-resident by capacity and the hand-rolled device-scope
// barrier cannot deadlock. Cooperative launch is NOT used (not graph-safe).

__global__ void __launch_bounds__(256, 2)
lstm_main(char* __restrict__ ws,
          const float* __restrict__ x,
          const float* __restrict__ wih0, const float* __restrict__ whh0, const float* __restrict__ eb0,
          const float* __restrict__ wih1, const float* __restrict__ whh1, const float* __restrict__ eb1,
          const float* __restrict__ dwih0, const float* __restrict__ dwhh0, const float* __restrict__ db0,
          const float* __restrict__ dwih1, const float* __restrict__ dwhh1, const float* __restrict__ db1,
          const float* __restrict__ linw, const float* __restrict__ linb,
          float* __restrict__ out)
{
    __shared__ f16   Wlds[16][1032];   // this WG's 16 weight rows (K-padded)
    __shared__ float Dp[4][64][17];    // per-wave partial gate sums

    const int wg = blockIdx.x, tid = threadIdx.x;
    const bool isL0 = wg < 128;
    const int u0 = (wg & 127) << 2;
    const int uu = tid & 3;
    int* bar = (int*)(ws + OFF_BAR);
    int bgen = 0;

    const f16* WX   = (const f16*)(ws + OFF_WX);
    const f16* WLIN = (const f16*)(ws + OFF_WLIN);
    f16* EH0 = (f16*)(ws + OFF_EH0);
    f16* EH1 = (f16*)(ws + OFF_EH1);
    f16* DH0 = (f16*)(ws + OFF_DH0);
    f16* DH1 = (f16*)(ws + OFF_DH1);

    // ---------------- encoder (layer1 pipelined one step behind layer0) ----------------
    if (isL0) load_wlds_f32(Wlds, wih0,  64, whh0, 512, u0, tid);
    else      load_wlds_f32(Wlds, wih1, 512, whh1, 512, u0, tid);
    __syncthreads();

    float ba[4];
    {
        const float* bs = isL0 ? eb0 : eb1;
        #pragma unroll
        for (int g = 0; g < 4; ++g) ba[g] = bs[(g << 9) + u0 + uu];
    }
    float creg = 0.f;   // cell state: fixed (m,unit) per thread across ALL phases

    for (int r = 0; r <= (int)NS; ++r) {
        if (isL0 && r < (int)NS) {
            // K = 64 (x_t, blocked) + 512 (h0_{t-1}) = 576 -> waves get 5/5/4/4
            rnn_round<5,false>(Wlds, Dp,
                      WX + r * 4096, 64,
                      EH0 + ((r + 1) & 1) * HSLOT,
                      576, 0, ba, creg,
                      EH0 + (r & 1) * HSLOT, u0, tid);
        } else if (!isL0 && r >= 1) {
            int t = r - 1;
            rnn_round<8,true>(Wlds, Dp,
                      EH0 + (t & 1) * HSLOT, 512,
                      EH1 + ((t + 1) & 1) * HSLOT,
                      1024, 0, ba, creg,
                      EH1 + (t & 1) * HSLOT, u0, tid);
        }
        grid_barrier(bar, wg, tid, bgen);
    }

    // ---------------- decoder setup (fold linear into layer0) ----------------
    float baI[4];
    if (isL0) {
        load_wlds_fold(Wlds, dwih0, linw, dwhh0, u0, tid);
        const int m = tid >> 2;
        const float* xr = x + m * (NS * NC) + (NS - 1) * NC;
        #pragma unroll
        for (int g = 0; g < 4; ++g) {
            int row = (g << 9) + u0 + uu;
            const float* wr = dwih0 + row * 64;
            float bsum = 0.f, xsum = 0.f;
            for (int c = 0; c < 64; ++c) { bsum += linb[c] * wr[c]; xsum += xr[c] * wr[c]; }
            ba[g]  = db0[row] + bsum;   // folded bias (t>=1)
            baI[g] = db0[row] + xsum;   // t==0 bias: x_last @ dec_Wih0^T + dec_b0
        }
    } else {
        load_wlds_f32(Wlds, dwih1, 512, dwhh1, 512, u0, tid);
        #pragma unroll
        for (int g = 0; g < 4; ++g) { ba[g] = db1[(g << 9) + u0 + uu]; baI[g] = 0.f; }
    }
    __syncthreads();

    // ---------------- decoder: 2 rounds/step; idle WGs 128..131 emit out_{t-1} ----------------
    for (int d = 0; d < 2 * (int)NT; ++d) {
        int t = d >> 1;
        if ((d & 1) == 0) {
            if (isL0) {
                if (t == 0) {
                    // only the Whh0 half is live (kStart=512): waves get 4 each
                    rnn_round<4,true>(Wlds, Dp, EH1 + HSLOT, 512, EH0 + HSLOT,
                              1024, 512, baI, creg,
                              DH0, u0, tid);
                } else {
                    rnn_round<8,true>(Wlds, Dp,
                              DH1 + ((t + 1) & 1) * HSLOT, 512,   // h1_{t-1} (Wfold)
                              DH0 + ((t + 1) & 1) * HSLOT,        // h0_{t-1} (Whh0)
                              1024, 0, ba, creg,
                              DH0 + (t & 1) * HSLOT, u0, tid);
                }
            } else if (wg < 132 && t >= 1) {
                out_gemm(DH1 + ((t - 1) & 1) * HSLOT, WLIN, linb, out, wg - 128, t - 1, tid);
            }
        } else {
            if (!isL0) {
                const f16* A1 = (t == 0) ? EH1 + HSLOT : DH1 + ((t + 1) & 1) * HSLOT;  // h1_{t-1} (Whh1)
                rnn_round<8,true>(Wlds, Dp,
                          DH0 + (t & 1) * HSLOT, 512,                                  // h0_t (Wih1)
                          A1, 1024, 0, ba, creg,
                          DH1 + (t & 1) * HSLOT, u0, tid);
            }
        }
        grid_barrier(bar, wg, tid, bgen);
    }

    // final out_{127} (h1_{127} is in DH1 slot 1; last grid_barrier already synced it)
    if (!isL0 && wg < 132)
        out_gemm(DH1 + HSLOT, WLIN, linb, out, wg - 128, (int)NT - 1, tid);
}

// ============================ host launch ============================

extern "C" void kernel_launch(void* const* d_in, const int* in_sizes, int n_in,
                              void* d_out, int out_size, void* d_ws, size_t ws_size,
                              hipStream_t stream)
{
    // setup_inputs() dict order: x, target_len, enc_Wih0, enc_Whh0, enc_b0,
    // enc_Wih1, enc_Whh1, enc_b1, dec_Wih0, dec_Whh0, dec_b0, dec_Wih1,
    // dec_Whh1, dec_b1, lin_W, lin_b.  (target_len at index 1!)
    const float* x     = (const float*)d_in[0];
    const float* wih0  = (const float*)d_in[2];
    const float* whh0  = (const float*)d_in[3];
    const float* eb0   = (const float*)d_in[4];
    const float* wih1  = (const float*)d_in[5];
    const float* whh1  = (const float*)d_in[6];
    const float* eb1   = (const float*)d_in[7];
    const float* dwih0 = (const float*)d_in[8];
    const float* dwhh0 = (const float*)d_in[9];
    const float* db0   = (const float*)d_in[10];
    const float* dwih1 = (const float*)d_in[11];
    const float* dwhh1 = (const float*)d_in[12];
    const float* db1   = (const float*)d_in[13];
    const float* linw  = (const float*)d_in[14];
    const float* linb  = (const float*)d_in[15];
    char* ws    = (char*)d_ws;
    float* outp = (float*)d_out;

    // tasks: 65536 (x blocked) + 8192 (linw) + 32768 (rings) + 512 (bar)
    //      = 107008 threads = EXACTLY 418 WGs of 256. (R12 launched 416 ->
    //        barrier block never re-zeroed -> deadlock. Keep this exact.)
    prep_convert<<<418, 256, 0, stream>>>(x, linw, ws);

    // plain launch (graph-capture safe); co-residency by capacity, see comment above
    lstm_main<<<256, 256, 0, stream>>>(ws, x, wih0, whh0, eb0, wih1, whh1, eb1,
                                       dwih0, dwhh0, db0, dwih1, dwhh1, db1,
                                       linw, linb, outp);
}